// Round 6
// baseline (172.481 us; speedup 1.0000x reference)
//
#include <hip/hip_runtime.h>

#define NPTS 512
#define BLOCK 256
#define XPS 68   // xp row stride (dwords): mult of 4 (16B rows), mod 32 = 4 staggers banks

// ---------------------------------------------------------------------------
// FUSED kernel: one wave per batch, no barriers, no intermediate ws.
//
// Evidence so far (R2-R5): four different load/reduce structures all land at
// 38-42 us for 117 MB logical (~2.9 TB/s) with VALU<15%, LDS ~0, occupancy
// ample -- the limiter is off-kernel (harness restore/poison writeback drain
// sharing HBM with our window). So this round stops re-arranging loads and
// instead removes the remaining controllable overheads:
//   - solve fused onto lane 0 of each wave (f64 latency chains overlap
//     across 8 waves/SIMD and across blocks' load phases)
//   - no ws round-trip, one dispatch instead of two (one launch gap saved)
//
// Loads: 48-B lane stride float4. Lane L, iter k owns points 4L+256k..+3:
//   3 src dwordx4 + 3 tgt dwordx4 + 1 w dwordx4, all within a dense 3072-B
//   window; 14 loads total per wave issued up-front (14 KB in flight).
// Reduce: wave-private transpose into padded xp[16][68] (2-way bank aliasing
//   everywhere = free), lane m+16q sums quarter q (4x ds_read_b128), 2x
//   shfl_xor folds quarters, 16 moments land in red[wave][*] via LDS.
// Solve (lane 0, f64): with T = sum(w)+eps:
//   H = M/T - (2 - W/T) * (m_s/T)(m_t/T)^T   (exact expansion of centered cov)
//   Jacobi eigendecomp of A = H^T H -> V; v3 := v1 x v2, u_i = H v_i
//   (Gram-Schmidt), u3 := u1 x u2; R = V U^T. Cross products force
//   det(U)=det(V)=+1 == reference's diag(1,1,sign(det)) reflection fix.
// ---------------------------------------------------------------------------
__global__ __launch_bounds__(BLOCK, 4) void wproc_fused(
    const float* __restrict__ src,
    const float* __restrict__ tgt,
    const float* __restrict__ wts,
    float* __restrict__ out,
    int B)
{
    const int wave = threadIdx.x >> 6;
    const int lane = threadIdx.x & 63;
    const int b = blockIdx.x * 4 + wave;   // grid = B/4 exact (B=8192)

    const float4* sb4 = (const float4*)(src + (size_t)b * (NPTS * 3));
    const float4* tb4 = (const float4*)(tgt + (size_t)b * (NPTS * 3));
    const float4* wb4 = (const float4*)(wts + (size_t)b * NPTS);

    // [W, m_s(3), m_t(3), M(9) row-major M_ij = sum w*src_i*tgt_j]
    float acc[16];
    #pragma unroll
    for (int i = 0; i < 16; ++i) acc[i] = 0.f;

    #pragma unroll
    for (int k = 0; k < 2; ++k) {
        // lane's 4 points: p0 = 4*lane + 256*k
        const int c3 = 3 * lane + 192 * k;   // float4 index of lane's 12 src/tgt floats
        float4 sv0 = sb4[c3 + 0], sv1 = sb4[c3 + 1], sv2 = sb4[c3 + 2];
        float4 tv0 = tb4[c3 + 0], tv1 = tb4[c3 + 1], tv2 = tb4[c3 + 2];
        float4 wv  = wb4[lane + 64 * k];

        const float sf[12] = { sv0.x, sv0.y, sv0.z, sv0.w, sv1.x, sv1.y,
                               sv1.z, sv1.w, sv2.x, sv2.y, sv2.z, sv2.w };
        const float tf[12] = { tv0.x, tv0.y, tv0.z, tv0.w, tv1.x, tv1.y,
                               tv1.z, tv1.w, tv2.x, tv2.y, tv2.z, tv2.w };
        const float wf[4] = { wv.x, wv.y, wv.z, wv.w };

        #pragma unroll
        for (int j = 0; j < 4; ++j) {
            float w = wf[j];
            w = (w < 0.f) ? 0.f : w;  // WEIGHT_THRESHOLD = 0.0
            const float sx = sf[3 * j + 0], sy = sf[3 * j + 1], sz = sf[3 * j + 2];
            const float tx = tf[3 * j + 0], ty = tf[3 * j + 1], tz = tf[3 * j + 2];
            acc[0] += w;
            acc[1] += w * sx; acc[2] += w * sy; acc[3] += w * sz;
            acc[4] += w * tx; acc[5] += w * ty; acc[6] += w * tz;
            const float wsx = w * sx, wsy = w * sy, wsz = w * sz;
            acc[7]  += wsx * tx; acc[8]  += wsx * ty; acc[9]  += wsx * tz;
            acc[10] += wsy * tx; acc[11] += wsy * ty; acc[12] += wsy * tz;
            acc[13] += wsz * tx; acc[14] += wsz * ty; acc[15] += wsz * tz;
        }
    }

    // ---- wave-private transpose-reduce (no block barrier anywhere) ----
    __shared__ float xp[4][16][XPS];
    __shared__ float red[4][16];
    #pragma unroll
    for (int m = 0; m < 16; ++m) xp[wave][m][lane] = acc[m];

    {
        const int m = lane & 15, q = lane >> 4;
        const float4* row = (const float4*)&xp[wave][m][0] + 4 * q;
        float4 a0 = row[0], a1 = row[1], a2 = row[2], a3 = row[3];
        a0.x += a1.x; a0.y += a1.y; a0.z += a1.z; a0.w += a1.w;
        a2.x += a3.x; a2.y += a3.y; a2.z += a3.z; a2.w += a3.w;
        a0.x += a2.x; a0.y += a2.y; a0.z += a2.z; a0.w += a2.w;
        float v = (a0.x + a0.y) + (a0.z + a0.w);
        v += __shfl_xor(v, 16, 64);
        v += __shfl_xor(v, 32, 64);
        if (q == 0) red[wave][m] = v;
    }
    // intra-wave DS ordering: lane 0's reads below wait on the writes above

    if (lane == 0) {
        double m[16];
        #pragma unroll
        for (int i = 0; i < 16; ++i) m[i] = (double)red[wave][i];

        const double T = m[0] + 1e-5;       // sum(w) + EPS
        const double f = 2.0 - m[0] / T;
        const double cs[3] = { m[1] / T, m[2] / T, m[3] / T };
        const double ct[3] = { m[4] / T, m[5] / T, m[6] / T };
        double H[3][3];
        for (int i = 0; i < 3; ++i)
            for (int j = 0; j < 3; ++j)
                H[i][j] = m[7 + i * 3 + j] / T - f * cs[i] * ct[j];

        // A = H^T H (symmetric PSD)
        double A[3][3];
        for (int i = 0; i < 3; ++i)
            for (int j = 0; j < 3; ++j)
                A[i][j] = H[0][i] * H[0][j] + H[1][i] * H[1][j] + H[2][i] * H[2][j];

        // Jacobi eigendecomposition: A = V diag V^T
        double V[3][3] = { {1, 0, 0}, {0, 1, 0}, {0, 0, 1} };
        for (int sweep = 0; sweep < 5; ++sweep) {
            for (int pair = 0; pair < 3; ++pair) {
                const int p = (pair == 2) ? 1 : 0;
                const int q = (pair == 0) ? 1 : 2;
                const double apq = A[p][q];
                if (apq == 0.0) continue;
                const double theta = (A[q][q] - A[p][p]) / (2.0 * apq);
                const double tt = ((theta >= 0.0) ? 1.0 : -1.0)
                                / (fabs(theta) + sqrt(theta * theta + 1.0));
                const double c = 1.0 / sqrt(tt * tt + 1.0);
                const double sn = tt * c;
                for (int k = 0; k < 3; ++k) {  // A <- A G
                    const double akp = A[k][p], akq = A[k][q];
                    A[k][p] = c * akp - sn * akq;
                    A[k][q] = sn * akp + c * akq;
                }
                for (int k = 0; k < 3; ++k) {  // A <- G^T A
                    const double apk = A[p][k], aqk = A[q][k];
                    A[p][k] = c * apk - sn * aqk;
                    A[q][k] = sn * apk + c * aqk;
                }
                for (int k = 0; k < 3; ++k) {  // V <- V G
                    const double vkp = V[k][p], vkq = V[k][q];
                    V[k][p] = c * vkp - sn * vkq;
                    V[k][q] = sn * vkp + c * vkq;
                }
            }
        }

        // sort eigenpairs descending
        const double lam[3] = { A[0][0], A[1][1], A[2][2] };
        int i0 = 0, i1 = 1, i2 = 2;
        if (lam[i0] < lam[i1]) { int tmp = i0; i0 = i1; i1 = tmp; }
        if (lam[i0] < lam[i2]) { int tmp = i0; i0 = i2; i2 = tmp; }
        if (lam[i1] < lam[i2]) { int tmp = i1; i1 = i2; i2 = tmp; }

        const double v1[3] = { V[0][i0], V[1][i0], V[2][i0] };
        const double v2[3] = { V[0][i1], V[1][i1], V[2][i1] };
        const double v3[3] = { v1[1] * v2[2] - v1[2] * v2[1],
                               v1[2] * v2[0] - v1[0] * v2[2],
                               v1[0] * v2[1] - v1[1] * v2[0] };

        double u1[3], u2[3], u3[3];
        for (int i = 0; i < 3; ++i)
            u1[i] = H[i][0] * v1[0] + H[i][1] * v1[1] + H[i][2] * v1[2];
        double n1 = sqrt(u1[0] * u1[0] + u1[1] * u1[1] + u1[2] * u1[2]);
        n1 = (n1 > 1e-30) ? n1 : 1e-30;
        for (int i = 0; i < 3; ++i) u1[i] /= n1;

        for (int i = 0; i < 3; ++i)
            u2[i] = H[i][0] * v2[0] + H[i][1] * v2[1] + H[i][2] * v2[2];
        const double d12 = u1[0] * u2[0] + u1[1] * u2[1] + u1[2] * u2[2];
        for (int i = 0; i < 3; ++i) u2[i] -= d12 * u1[i];
        double n2 = sqrt(u2[0] * u2[0] + u2[1] * u2[1] + u2[2] * u2[2]);
        n2 = (n2 > 1e-30) ? n2 : 1e-30;
        for (int i = 0; i < 3; ++i) u2[i] /= n2;

        u3[0] = u1[1] * u2[2] - u1[2] * u2[1];
        u3[1] = u1[2] * u2[0] - u1[0] * u2[2];
        u3[2] = u1[0] * u2[1] - u1[1] * u2[0];

        double R[3][3];
        for (int i = 0; i < 3; ++i)
            for (int j = 0; j < 3; ++j)
                R[i][j] = v1[i] * u1[j] + v2[i] * u2[j] + v3[i] * u3[j];

        double tv[3];
        for (int i = 0; i < 3; ++i)
            tv[i] = ct[i] - (R[i][0] * cs[0] + R[i][1] * cs[1] + R[i][2] * cs[2]);

        float* outR = out + (size_t)b * 9;
        for (int i = 0; i < 3; ++i)
            for (int j = 0; j < 3; ++j)
                outR[i * 3 + j] = (float)R[i][j];
        float* outT = out + (size_t)B * 9 + (size_t)b * 3;
        for (int i = 0; i < 3; ++i) outT[i] = (float)tv[i];
    }
}

extern "C" void kernel_launch(void* const* d_in, const int* in_sizes, int n_in,
                              void* d_out, int out_size, void* d_ws, size_t ws_size,
                              hipStream_t stream) {
    const float* src = (const float*)d_in[0];
    const float* tgt = (const float*)d_in[1];
    const float* wts = (const float*)d_in[2];
    float* out = (float*)d_out;
    const int B = out_size / 12;  // 9 (R) + 3 (t) floats per batch; B=8192

    wproc_fused<<<B / 4, BLOCK, 0, stream>>>(src, tgt, wts, out, B);
}

// Round 7
// 151.616 us; speedup vs baseline: 1.1376x; 1.1376x over previous
//
#include <hip/hip_runtime.h>

#define NPTS 512
#define BLOCK 256
#define XPS 68   // xp row stride (dwords): mult of 4 (16B rows), mod 32 = 4 staggers banks

typedef float v4f __attribute__((ext_vector_type(4)));

// ---------------------------------------------------------------------------
// Kernel 1: per-batch weighted moments — one wave per batch, no barriers.
// R7 change vs R5: dwordx4 NONTEMPORAL loads (global_load_dwordx4 nt).
// Rationale: R3/R4/R5 all plateau at ~40 us (~2.9 TB/s logical) with every
// pipe <15% busy — consistent with a per-CU outstanding-line-fill (MSHR)
// limit on streaming reads, not with BW/VALU/DS limits. NT streaming hints
// are the one lever that changes line-allocation behavior.
//
// Loads: lane L, iter k in {0,1} owns points 4L+256k..+3 = 3 src dwordx4 +
// 3 tgt dwordx4 + 1 w dwordx4 (48-B lane stride, dense 3072-B wave window).
// Reduce: wave-private transpose into padded xp[16][68] (2-way bank aliasing
// everywhere = free), lane m+16q sums quarter q (4x ds_read_b128), 2x
// shfl_xor; lane m<16 stores moment m. Intra-wave DS ordering, no barriers.
// ---------------------------------------------------------------------------
__global__ __launch_bounds__(BLOCK) void wproc_moments(
    const float* __restrict__ src,
    const float* __restrict__ tgt,
    const float* __restrict__ wts,
    float* __restrict__ ws)
{
    const int wave = threadIdx.x >> 6;
    const int lane = threadIdx.x & 63;
    const int b = blockIdx.x * 4 + wave;   // grid = B/4 exact (B=8192)

    const v4f* sb4 = (const v4f*)(src + (size_t)b * (NPTS * 3));
    const v4f* tb4 = (const v4f*)(tgt + (size_t)b * (NPTS * 3));
    const v4f* wb4 = (const v4f*)(wts + (size_t)b * NPTS);

    // [W, m_s(3), m_t(3), M(9) row-major M_ij = sum w*src_i*tgt_j]
    float acc[16];
    #pragma unroll
    for (int i = 0; i < 16; ++i) acc[i] = 0.f;

    #pragma unroll
    for (int k = 0; k < 2; ++k) {
        const int c3 = 3 * lane + 192 * k;   // float4 index of lane's 12 src/tgt floats
        v4f sv0 = __builtin_nontemporal_load(&sb4[c3 + 0]);
        v4f sv1 = __builtin_nontemporal_load(&sb4[c3 + 1]);
        v4f sv2 = __builtin_nontemporal_load(&sb4[c3 + 2]);
        v4f tv0 = __builtin_nontemporal_load(&tb4[c3 + 0]);
        v4f tv1 = __builtin_nontemporal_load(&tb4[c3 + 1]);
        v4f tv2 = __builtin_nontemporal_load(&tb4[c3 + 2]);
        v4f wv  = __builtin_nontemporal_load(&wb4[lane + 64 * k]);

        const float sf[12] = { sv0.x, sv0.y, sv0.z, sv0.w, sv1.x, sv1.y,
                               sv1.z, sv1.w, sv2.x, sv2.y, sv2.z, sv2.w };
        const float tf[12] = { tv0.x, tv0.y, tv0.z, tv0.w, tv1.x, tv1.y,
                               tv1.z, tv1.w, tv2.x, tv2.y, tv2.z, tv2.w };
        const float wf[4] = { wv.x, wv.y, wv.z, wv.w };

        #pragma unroll
        for (int j = 0; j < 4; ++j) {
            float w = wf[j];
            w = (w < 0.f) ? 0.f : w;  // WEIGHT_THRESHOLD = 0.0
            const float sx = sf[3 * j + 0], sy = sf[3 * j + 1], sz = sf[3 * j + 2];
            const float tx = tf[3 * j + 0], ty = tf[3 * j + 1], tz = tf[3 * j + 2];
            acc[0] += w;
            acc[1] += w * sx; acc[2] += w * sy; acc[3] += w * sz;
            acc[4] += w * tx; acc[5] += w * ty; acc[6] += w * tz;
            const float wsx = w * sx, wsy = w * sy, wsz = w * sz;
            acc[7]  += wsx * tx; acc[8]  += wsx * ty; acc[9]  += wsx * tz;
            acc[10] += wsy * tx; acc[11] += wsy * ty; acc[12] += wsy * tz;
            acc[13] += wsz * tx; acc[14] += wsz * ty; acc[15] += wsz * tz;
        }
    }

    // ---- wave-private transpose-reduce (no block barrier anywhere) ----
    __shared__ float xp[4][16][XPS];
    #pragma unroll
    for (int m = 0; m < 16; ++m) xp[wave][m][lane] = acc[m];

    {
        const int m = lane & 15, q = lane >> 4;
        const float4* row = (const float4*)&xp[wave][m][0] + 4 * q;
        float4 a0 = row[0], a1 = row[1], a2 = row[2], a3 = row[3];
        a0.x += a1.x; a0.y += a1.y; a0.z += a1.z; a0.w += a1.w;
        a2.x += a3.x; a2.y += a3.y; a2.z += a3.z; a2.w += a3.w;
        a0.x += a2.x; a0.y += a2.y; a0.z += a2.z; a0.w += a2.w;
        float v = (a0.x + a0.y) + (a0.z + a0.w);
        v += __shfl_xor(v, 16, 64);
        v += __shfl_xor(v, 32, 64);
        if (q == 0) ws[(size_t)b * 16 + m] = v;
    }
}

// ---------------------------------------------------------------------------
// Kernel 2: per-batch 3x3 Procrustes solve, one lane per batch — 128 dense
// f64 chains total (R6 proved per-wave fusion inflates this 64x; keep split).
//
// Algebra: with T = sum(w)+eps:
//   H = M/T - (2 - W/T) * (m_s/T)(m_t/T)^T   (exact expansion of centered cov)
// SVD-free rotation: Jacobi eigendecomp of A = H^T H -> V; v3 := v1 x v2,
// u_i = H v_i (Gram-Schmidt), u3 := u1 x u2; R = V U^T. Cross products force
// det(U)=det(V)=+1 == reference's diag(1,1,sign(det)) reflection fix.
// ---------------------------------------------------------------------------
__global__ __launch_bounds__(BLOCK) void wproc_solve(
    const float* __restrict__ ws,
    float* __restrict__ out,
    int B)
{
    const int b = blockIdx.x * BLOCK + threadIdx.x;
    if (b >= B) return;

    double m[16];
    #pragma unroll
    for (int i = 0; i < 16; ++i) m[i] = (double)ws[(size_t)b * 16 + i];

    const double T = m[0] + 1e-5;       // sum(w) + EPS
    const double f = 2.0 - m[0] / T;
    const double cs[3] = { m[1] / T, m[2] / T, m[3] / T };
    const double ct[3] = { m[4] / T, m[5] / T, m[6] / T };
    double H[3][3];
    for (int i = 0; i < 3; ++i)
        for (int j = 0; j < 3; ++j)
            H[i][j] = m[7 + i * 3 + j] / T - f * cs[i] * ct[j];

    // A = H^T H (symmetric PSD)
    double A[3][3];
    for (int i = 0; i < 3; ++i)
        for (int j = 0; j < 3; ++j)
            A[i][j] = H[0][i] * H[0][j] + H[1][i] * H[1][j] + H[2][i] * H[2][j];

    // Jacobi eigendecomposition: A = V diag V^T
    double V[3][3] = { {1, 0, 0}, {0, 1, 0}, {0, 0, 1} };
    for (int sweep = 0; sweep < 5; ++sweep) {
        for (int pair = 0; pair < 3; ++pair) {
            const int p = (pair == 2) ? 1 : 0;
            const int q = (pair == 0) ? 1 : 2;
            const double apq = A[p][q];
            if (apq == 0.0) continue;
            const double theta = (A[q][q] - A[p][p]) / (2.0 * apq);
            const double tt = ((theta >= 0.0) ? 1.0 : -1.0)
                            / (fabs(theta) + sqrt(theta * theta + 1.0));
            const double c = 1.0 / sqrt(tt * tt + 1.0);
            const double sn = tt * c;
            for (int k = 0; k < 3; ++k) {  // A <- A G
                const double akp = A[k][p], akq = A[k][q];
                A[k][p] = c * akp - sn * akq;
                A[k][q] = sn * akp + c * akq;
            }
            for (int k = 0; k < 3; ++k) {  // A <- G^T A
                const double apk = A[p][k], aqk = A[q][k];
                A[p][k] = c * apk - sn * aqk;
                A[q][k] = sn * apk + c * aqk;
            }
            for (int k = 0; k < 3; ++k) {  // V <- V G
                const double vkp = V[k][p], vkq = V[k][q];
                V[k][p] = c * vkp - sn * vkq;
                V[k][q] = sn * vkp + c * vkq;
            }
        }
    }

    // sort eigenpairs descending
    const double lam[3] = { A[0][0], A[1][1], A[2][2] };
    int i0 = 0, i1 = 1, i2 = 2;
    if (lam[i0] < lam[i1]) { int tmp = i0; i0 = i1; i1 = tmp; }
    if (lam[i0] < lam[i2]) { int tmp = i0; i0 = i2; i2 = tmp; }
    if (lam[i1] < lam[i2]) { int tmp = i1; i1 = i2; i2 = tmp; }

    const double v1[3] = { V[0][i0], V[1][i0], V[2][i0] };
    const double v2[3] = { V[0][i1], V[1][i1], V[2][i1] };
    const double v3[3] = { v1[1] * v2[2] - v1[2] * v2[1],
                           v1[2] * v2[0] - v1[0] * v2[2],
                           v1[0] * v2[1] - v1[1] * v2[0] };

    double u1[3], u2[3], u3[3];
    for (int i = 0; i < 3; ++i)
        u1[i] = H[i][0] * v1[0] + H[i][1] * v1[1] + H[i][2] * v1[2];
    double n1 = sqrt(u1[0] * u1[0] + u1[1] * u1[1] + u1[2] * u1[2]);
    n1 = (n1 > 1e-30) ? n1 : 1e-30;
    for (int i = 0; i < 3; ++i) u1[i] /= n1;

    for (int i = 0; i < 3; ++i)
        u2[i] = H[i][0] * v2[0] + H[i][1] * v2[1] + H[i][2] * v2[2];
    const double d12 = u1[0] * u2[0] + u1[1] * u2[1] + u1[2] * u2[2];
    for (int i = 0; i < 3; ++i) u2[i] -= d12 * u1[i];
    double n2 = sqrt(u2[0] * u2[0] + u2[1] * u2[1] + u2[2] * u2[2]);
    n2 = (n2 > 1e-30) ? n2 : 1e-30;
    for (int i = 0; i < 3; ++i) u2[i] /= n2;

    u3[0] = u1[1] * u2[2] - u1[2] * u2[1];
    u3[1] = u1[2] * u2[0] - u1[0] * u2[2];
    u3[2] = u1[0] * u2[1] - u1[1] * u2[0];

    double R[3][3];
    for (int i = 0; i < 3; ++i)
        for (int j = 0; j < 3; ++j)
            R[i][j] = v1[i] * u1[j] + v2[i] * u2[j] + v3[i] * u3[j];

    double tv[3];
    for (int i = 0; i < 3; ++i)
        tv[i] = ct[i] - (R[i][0] * cs[0] + R[i][1] * cs[1] + R[i][2] * cs[2]);

    float* outR = out + (size_t)b * 9;
    for (int i = 0; i < 3; ++i)
        for (int j = 0; j < 3; ++j)
            outR[i * 3 + j] = (float)R[i][j];
    float* outT = out + (size_t)B * 9 + (size_t)b * 3;
    for (int i = 0; i < 3; ++i) outT[i] = (float)tv[i];
}

extern "C" void kernel_launch(void* const* d_in, const int* in_sizes, int n_in,
                              void* d_out, int out_size, void* d_ws, size_t ws_size,
                              hipStream_t stream) {
    const float* src = (const float*)d_in[0];
    const float* tgt = (const float*)d_in[1];
    const float* wts = (const float*)d_in[2];
    float* out = (float*)d_out;
    float* ws = (float*)d_ws;   // 16 floats per batch = 512 KB
    const int B = out_size / 12;  // 9 (R) + 3 (t) floats per batch; B=8192

    wproc_moments<<<B / 4, BLOCK, 0, stream>>>(src, tgt, wts, ws);
    wproc_solve<<<(B + BLOCK - 1) / BLOCK, BLOCK, 0, stream>>>(ws, out, B);
}

// Round 8
// 144.809 us; speedup vs baseline: 1.1911x; 1.0470x over previous
//
#include <hip/hip_runtime.h>

#define NPTS 512
#define BLOCK 256
#define XPS 68   // xp row stride (dwords): mult of 4 (16B rows), mod 32 = 4 staggers banks

#define GLOBAL_AS(p) ((const __attribute__((address_space(1))) void*)(p))
#define LDS_AS(p)    ((__attribute__((address_space(3))) void*)(p))

// ---------------------------------------------------------------------------
// Kernel 1: per-batch weighted moments — R8: global_load_lds staging.
//
// R3-R7 evidence: five load structures all cap at 2.76-2.95 TB/s logical
// read rate with every pipe <15% busy. The m13 "6.29 TB/s" HBM ceiling is a
// copy counted read+write => its READ stream ran ~3.15 TB/s; the write-only
// fill does 6.5. Hypothesis: plain vector-load read path caps near 3.1 TB/s.
// Final falsification: __builtin_amdgcn_global_load_lds (width=16) is a
// physically different path (DMA direct to LDS, no L1->VGPR return). If this
// also lands at ~40 us, the read-path ceiling is universal and we are at
// ~93% of it.
//
// Staging: one block per batch; src(6 KB)+tgt(6 KB)+w(2 KB) = 14 chunks of
// 1 KB; wave w issues chunks c = w, w+4, ... Each instr: per-lane global
// addr (base + c*1024 + lane*16), wave-uniform LDS dest (smem + c*1024) --
// HW writes lane L at dest + 16L (contiguous, matches layout).
// Accumulate: thread t handles points t, t+256 (stride-3 LDS reads = 2-way
// bank aliasing = free). Reduce: per-wave transpose into xp[16][68] (overlaid
// on the staging buffer after a barrier), quarter-sums via 4x ds_read_b128,
// 2x shfl_xor, cross-wave combine.
// ---------------------------------------------------------------------------
__global__ __launch_bounds__(BLOCK) void wproc_moments(
    const float* __restrict__ src,
    const float* __restrict__ tgt,
    const float* __restrict__ wts,
    float* __restrict__ ws)
{
    const int b = blockIdx.x;
    const int t = threadIdx.x;
    const int wave = t >> 6, lane = t & 63;

    // phase 1: 14336 B staging buffer; phase 2: xp[4][16][68] = 17408 B
    __shared__ __align__(16) char smem[4 * 16 * XPS * 4];
    __shared__ float red[4][16];

    const char* sb = (const char*)(src + (size_t)b * (NPTS * 3));
    const char* tb = (const char*)(tgt + (size_t)b * (NPTS * 3));
    const char* wb = (const char*)(wts + (size_t)b * NPTS);

    // ---- direct-to-LDS staging: 14 x 1KB chunks round-robined over waves ----
    for (int c = wave; c < 14; c += 4) {
        const char* g;
        if (c < 6)       g = sb + (size_t)c * 1024;
        else if (c < 12) g = tb + (size_t)(c - 6) * 1024;
        else             g = wb + (size_t)(c - 12) * 1024;
        __builtin_amdgcn_global_load_lds(
            GLOBAL_AS(g + lane * 16),
            LDS_AS(smem + c * 1024),
            16, 0, 0);
    }
    __syncthreads();   // compiler drains vmcnt before the barrier

    const float* s_s = (const float*)smem;            // [0, 6144)
    const float* s_t = (const float*)(smem + 6144);   // [6144, 12288)
    const float* s_w = (const float*)(smem + 12288);  // [12288, 14336)

    // ---- accumulate 16 moments over 2 points ----
    // [W, m_s(3), m_t(3), M(9) row-major M_ij = sum w*src_i*tgt_j]
    float acc[16];
    #pragma unroll
    for (int i = 0; i < 16; ++i) acc[i] = 0.f;

    #pragma unroll
    for (int k = 0; k < 2; ++k) {
        const int p = t + k * 256;
        float w = s_w[p];
        w = (w < 0.f) ? 0.f : w;  // WEIGHT_THRESHOLD = 0.0
        const float sx = s_s[3 * p + 0], sy = s_s[3 * p + 1], sz = s_s[3 * p + 2];
        const float tx = s_t[3 * p + 0], ty = s_t[3 * p + 1], tz = s_t[3 * p + 2];
        acc[0] += w;
        acc[1] += w * sx; acc[2] += w * sy; acc[3] += w * sz;
        acc[4] += w * tx; acc[5] += w * ty; acc[6] += w * tz;
        const float wsx = w * sx, wsy = w * sy, wsz = w * sz;
        acc[7]  += wsx * tx; acc[8]  += wsx * ty; acc[9]  += wsx * tz;
        acc[10] += wsy * tx; acc[11] += wsy * ty; acc[12] += wsy * tz;
        acc[13] += wsz * tx; acc[14] += wsz * ty; acc[15] += wsz * tz;
    }
    __syncthreads();   // all point reads done before xp overlays the buffer

    float (*xp)[16][XPS] = (float (*)[16][XPS])smem;
    #pragma unroll
    for (int m = 0; m < 16; ++m) xp[wave][m][lane] = acc[m];

    // wave-private: lane m+16q sums quarter q of row m (in-order DS, no barrier)
    {
        const int m = lane & 15, q = lane >> 4;
        const float4* row = (const float4*)&xp[wave][m][0] + 4 * q;
        float4 a0 = row[0], a1 = row[1], a2 = row[2], a3 = row[3];
        a0.x += a1.x; a0.y += a1.y; a0.z += a1.z; a0.w += a1.w;
        a2.x += a3.x; a2.y += a3.y; a2.z += a3.z; a2.w += a3.w;
        a0.x += a2.x; a0.y += a2.y; a0.z += a2.z; a0.w += a2.w;
        float v = (a0.x + a0.y) + (a0.z + a0.w);
        v += __shfl_xor(v, 16, 64);
        v += __shfl_xor(v, 32, 64);
        if (q == 0) red[wave][m] = v;
    }
    __syncthreads();

    if (t < 16) {
        ws[(size_t)b * 16 + t] =
            (red[0][t] + red[1][t]) + (red[2][t] + red[3][t]);
    }
}

// ---------------------------------------------------------------------------
// Kernel 2: per-batch 3x3 Procrustes solve, one lane per batch — 128 dense
// f64 chains total (R6 proved per-wave fusion inflates this 64x; keep split).
//
// Algebra: with T = sum(w)+eps:
//   H = M/T - (2 - W/T) * (m_s/T)(m_t/T)^T   (exact expansion of centered cov)
// SVD-free rotation: Jacobi eigendecomp of A = H^T H -> V; v3 := v1 x v2,
// u_i = H v_i (Gram-Schmidt), u3 := u1 x u2; R = V U^T. Cross products force
// det(U)=det(V)=+1 == reference's diag(1,1,sign(det)) reflection fix.
// ---------------------------------------------------------------------------
__global__ __launch_bounds__(BLOCK) void wproc_solve(
    const float* __restrict__ ws,
    float* __restrict__ out,
    int B)
{
    const int b = blockIdx.x * BLOCK + threadIdx.x;
    if (b >= B) return;

    double m[16];
    #pragma unroll
    for (int i = 0; i < 16; ++i) m[i] = (double)ws[(size_t)b * 16 + i];

    const double T = m[0] + 1e-5;       // sum(w) + EPS
    const double f = 2.0 - m[0] / T;
    const double cs[3] = { m[1] / T, m[2] / T, m[3] / T };
    const double ct[3] = { m[4] / T, m[5] / T, m[6] / T };
    double H[3][3];
    for (int i = 0; i < 3; ++i)
        for (int j = 0; j < 3; ++j)
            H[i][j] = m[7 + i * 3 + j] / T - f * cs[i] * ct[j];

    // A = H^T H (symmetric PSD)
    double A[3][3];
    for (int i = 0; i < 3; ++i)
        for (int j = 0; j < 3; ++j)
            A[i][j] = H[0][i] * H[0][j] + H[1][i] * H[1][j] + H[2][i] * H[2][j];

    // Jacobi eigendecomposition: A = V diag V^T
    double V[3][3] = { {1, 0, 0}, {0, 1, 0}, {0, 0, 1} };
    for (int sweep = 0; sweep < 5; ++sweep) {
        for (int pair = 0; pair < 3; ++pair) {
            const int p = (pair == 2) ? 1 : 0;
            const int q = (pair == 0) ? 1 : 2;
            const double apq = A[p][q];
            if (apq == 0.0) continue;
            const double theta = (A[q][q] - A[p][p]) / (2.0 * apq);
            const double tt = ((theta >= 0.0) ? 1.0 : -1.0)
                            / (fabs(theta) + sqrt(theta * theta + 1.0));
            const double c = 1.0 / sqrt(tt * tt + 1.0);
            const double sn = tt * c;
            for (int k = 0; k < 3; ++k) {  // A <- A G
                const double akp = A[k][p], akq = A[k][q];
                A[k][p] = c * akp - sn * akq;
                A[k][q] = sn * akp + c * akq;
            }
            for (int k = 0; k < 3; ++k) {  // A <- G^T A
                const double apk = A[p][k], aqk = A[q][k];
                A[p][k] = c * apk - sn * aqk;
                A[q][k] = sn * apk + c * aqk;
            }
            for (int k = 0; k < 3; ++k) {  // V <- V G
                const double vkp = V[k][p], vkq = V[k][q];
                V[k][p] = c * vkp - sn * vkq;
                V[k][q] = sn * vkp + c * vkq;
            }
        }
    }

    // sort eigenpairs descending
    const double lam[3] = { A[0][0], A[1][1], A[2][2] };
    int i0 = 0, i1 = 1, i2 = 2;
    if (lam[i0] < lam[i1]) { int tmp = i0; i0 = i1; i1 = tmp; }
    if (lam[i0] < lam[i2]) { int tmp = i0; i0 = i2; i2 = tmp; }
    if (lam[i1] < lam[i2]) { int tmp = i1; i1 = i2; i2 = tmp; }

    const double v1[3] = { V[0][i0], V[1][i0], V[2][i0] };
    const double v2[3] = { V[0][i1], V[1][i1], V[2][i1] };
    const double v3[3] = { v1[1] * v2[2] - v1[2] * v2[1],
                           v1[2] * v2[0] - v1[0] * v2[2],
                           v1[0] * v2[1] - v1[1] * v2[0] };

    double u1[3], u2[3], u3[3];
    for (int i = 0; i < 3; ++i)
        u1[i] = H[i][0] * v1[0] + H[i][1] * v1[1] + H[i][2] * v1[2];
    double n1 = sqrt(u1[0] * u1[0] + u1[1] * u1[1] + u1[2] * u1[2]);
    n1 = (n1 > 1e-30) ? n1 : 1e-30;
    for (int i = 0; i < 3; ++i) u1[i] /= n1;

    for (int i = 0; i < 3; ++i)
        u2[i] = H[i][0] * v2[0] + H[i][1] * v2[1] + H[i][2] * v2[2];
    const double d12 = u1[0] * u2[0] + u1[1] * u2[1] + u1[2] * u2[2];
    for (int i = 0; i < 3; ++i) u2[i] -= d12 * u1[i];
    double n2 = sqrt(u2[0] * u2[0] + u2[1] * u2[1] + u2[2] * u2[2]);
    n2 = (n2 > 1e-30) ? n2 : 1e-30;
    for (int i = 0; i < 3; ++i) u2[i] /= n2;

    u3[0] = u1[1] * u2[2] - u1[2] * u2[1];
    u3[1] = u1[2] * u2[0] - u1[0] * u2[2];
    u3[2] = u1[0] * u2[1] - u1[1] * u2[0];

    double R[3][3];
    for (int i = 0; i < 3; ++i)
        for (int j = 0; j < 3; ++j)
            R[i][j] = v1[i] * u1[j] + v2[i] * u2[j] + v3[i] * u3[j];

    double tv[3];
    for (int i = 0; i < 3; ++i)
        tv[i] = ct[i] - (R[i][0] * cs[0] + R[i][1] * cs[1] + R[i][2] * cs[2]);

    float* outR = out + (size_t)b * 9;
    for (int i = 0; i < 3; ++i)
        for (int j = 0; j < 3; ++j)
            outR[i * 3 + j] = (float)R[i][j];
    float* outT = out + (size_t)B * 9 + (size_t)b * 3;
    for (int i = 0; i < 3; ++i) outT[i] = (float)tv[i];
}

extern "C" void kernel_launch(void* const* d_in, const int* in_sizes, int n_in,
                              void* d_out, int out_size, void* d_ws, size_t ws_size,
                              hipStream_t stream) {
    const float* src = (const float*)d_in[0];
    const float* tgt = (const float*)d_in[1];
    const float* wts = (const float*)d_in[2];
    float* out = (float*)d_out;
    float* ws = (float*)d_ws;   // 16 floats per batch = 512 KB
    const int B = out_size / 12;  // 9 (R) + 3 (t) floats per batch; B=8192

    wproc_moments<<<B, BLOCK, 0, stream>>>(src, tgt, wts, ws);
    wproc_solve<<<(B + BLOCK - 1) / BLOCK, BLOCK, 0, stream>>>(ws, out, B);
}